// Round 17
// baseline (136.662 us; speedup 1.0000x reference)
//
#include <hip/hip_runtime.h>
#include <hip/hip_bf16.h>
#include <stdint.h>

// KipfMLPGNN: B=32, N=64 nodes, D=128, H=256, L=3 layers.
// v17 = v16 fusion re-tiled for occupancy:
//  - NR=4, grid (16,32,2) = 1024 blocks = 4 blocks/CU = 16 waves/CU (2x v16).
//  - T-GEMM operand-swapped: mfma(W1_frag, E_frag) -> output transposed
//    (lane col = node, rows = h) -> Ts/Tr stores are contiguous b64 writes
//    (16/wave, ~2-way conflicts) instead of 64 scalar ds_write_u16.
//  - T-GEMM accumulates in regs; Ts LDS (32KB) aliases Els (16KB) after a
//    barrier -> LDS 36KB -> 4 blocks/CU fits.
//  - E never materialized: E' = E0 + Sum(SpA) [+ Sum(SpB)] on the fly.

#define NB 32
#define NN 64
#define DD 128
#define HH 256

typedef __attribute__((ext_vector_type(4))) float f32x4;
typedef __attribute__((ext_vector_type(8))) _Float16 f16x8;

__device__ __forceinline__ uint64_t cvt4h(f32x4 v) {
  union { _Float16 h[4]; uint64_t u; } x;
  x.h[0] = (_Float16)v[0]; x.h[1] = (_Float16)v[1];
  x.h[2] = (_Float16)v[2]; x.h[3] = (_Float16)v[3];
  return x.u;
}

// Fused setup: gather E0 (256 blk) | W1/W2 -> fp16 (192 blk)
__global__ __launch_bounds__(256) void k_setup(const int* __restrict__ x,
                                               const float* __restrict__ table,
                                               float* __restrict__ E0,
                                               const float* __restrict__ W1_0,
                                               const float* __restrict__ W1_1,
                                               const float* __restrict__ W2_0,
                                               const float* __restrict__ W2_1,
                                               _Float16* __restrict__ W1fp,
                                               _Float16* __restrict__ W2fp) {
  int bid = blockIdx.x, t = threadIdx.x;
  if (bid < 256) {
    int i = bid * 256 + t;
    int node = i >> 5;
    ((f32x4*)E0)[i] = ((const f32x4*)table)[(size_t)x[node] * 32 + (i & 31)];
  } else {
    int tid = (bid - 256) * 256 + t;     // 49152 f32x4 chunks
    const float* src; uint64_t* dst; int off;
    if (tid < 32768) {
      src = (tid < 16384) ? W1_0 : W1_1;
      off = tid & 16383;
      dst = (uint64_t*)W1fp + (tid >> 14) * 16384 + off;
    } else {
      int t2 = tid - 32768;
      src = (t2 < 8192) ? W2_0 : W2_1;
      off = t2 & 8191;
      dst = (uint64_t*)W2fp + (t2 >> 13) * 8192 + off;
    }
    *dst = cvt4h(((const f32x4*)src)[off]);
  }
}

// k_fused<NSP,NR>: grid (64/NR/... , 32, 2) = (rg, b, p).
// NSP = prior Sp generations folded into E'. NR = r's per block.
template <int NSP, int NR>
__global__ __launch_bounds__(256) void k_fused(
    const float* __restrict__ E0,
    const float* __restrict__ spA,
    const float* __restrict__ spB,
    float* __restrict__ spOut,
    const _Float16* __restrict__ W1fp,
    const _Float16* __restrict__ W2fp,
    const float* __restrict__ b1_0, const float* __restrict__ b1_1,
    const float* __restrict__ b2_0, const float* __restrict__ b2_1,
    const int* __restrict__ arcs) {
  __shared__ char lds[36864];
  char* Els = lds;            // [64 node][256 B] E' f16, swizzled (phase 1-2)
  char* Tsl = lds;            // [64 c][512 B] Ts f16, swizzled (phase 3+, aliases Els)
  char* Trl = lds + 32768;    // [NR<=8 r][512 B] Tr f16 (+b1)

  int t = threadIdx.x;
  int rg = blockIdx.x, b = blockIdx.y, p = blockIdx.z;
  int rbase = rg * NR;
  int lane = t & 63, w = t >> 6, col = lane & 15, khi = lane >> 4;
  const f32x4 z4 = {0.f, 0.f, 0.f, 0.f};

  // ---- phase 1: stage E' = E0 [+ SpA] [+ SpB] -> Els (f16, swizzled) ----
  {
    const f32x4* e0 = (const f32x4*)(E0 + (size_t)b * NN * DD);
    const f32x4* a0 = (const f32x4*)(spA + (size_t)b * NN * DD);
    const f32x4* a1 = (const f32x4*)(spA + (size_t)(NB + b) * NN * DD);
    const f32x4* c0 = (const f32x4*)(spB + (size_t)b * NN * DD);
    const f32x4* c1 = (const f32x4*)(spB + (size_t)(NB + b) * NN * DD);
#pragma unroll
    for (int ii = 0; ii < 8; ++ii) {
      int idx = ii * 256 + t;          // node=idx>>5, ck=idx&31
      f32x4 v = e0[idx];
      if (NSP >= 1) v += a0[idx] + a1[idx];
      if (NSP >= 2) v += c0[idx] + c1[idx];
      int node = idx >> 5, ck = idx & 31;
      *(uint64_t*)(Els + node * 256 + ((ck * 8) ^ ((node & 7) << 4))) = cvt4h(v);
    }
  }
  __syncthreads();

  // ---- phase 2: T-GEMM in regs, operand-swapped (out: rows=h, cols=node) --
  const _Float16* Wq = W1fp + p * 65536;     // [256 h][256 in]
  const float* b1p = p ? b1_1 : b1_0;
  int g = rbase >> 4, cb = rbase & 15;       // node-group for Tr, col base

  f32x4 taccS[4][4];                         // [mt_h][nt_c]
  f32x4 taccR[4];                            // [mt_h], B = node group g
#pragma unroll
  for (int mt = 0; mt < 4; ++mt) {
#pragma unroll
    for (int nt = 0; nt < 4; ++nt) taccS[mt][nt] = z4;
    taccR[mt] = z4;
  }
#pragma unroll
  for (int ks = 0; ks < 4; ++ks) {
    f16x8 be[4];
#pragma unroll
    for (int nt = 0; nt < 4; ++nt) {
      int c = nt * 16 + col;
      be[nt] = *(const f16x8*)(Els + c * 256 + ((ks * 64 + khi * 16) ^ ((c & 7) << 4)));
    }
    int gc = g * 16 + col;
    f16x8 beg = *(const f16x8*)(Els + gc * 256 + ((ks * 64 + khi * 16) ^ ((gc & 7) << 4)));
#pragma unroll
    for (int mt = 0; mt < 4; ++mt) {
      int h = w * 64 + mt * 16 + col;
      f16x8 aw = *(const f16x8*)(Wq + h * 256 + ks * 32 + khi * 8);
#pragma unroll
      for (int nt = 0; nt < 4; ++nt)
        taccS[mt][nt] = __builtin_amdgcn_mfma_f32_16x16x32_f16(aw, be[nt],
                                                               taccS[mt][nt], 0, 0, 0);
      f16x8 awr = *(const f16x8*)(Wq + h * 256 + 128 + ks * 32 + khi * 8);
      taccR[mt] = __builtin_amdgcn_mfma_f32_16x16x32_f16(awr, beg,
                                                         taccR[mt], 0, 0, 0);
    }
  }
  __syncthreads();   // all Els reads done; Tsl may overwrite

  // ---- phase 3: write Ts/Tr to LDS (contiguous b64 per fragment) ----
#pragma unroll
  for (int mt = 0; mt < 4; ++mt) {
    int h0 = w * 64 + mt * 16 + khi * 4;
#pragma unroll
    for (int nt = 0; nt < 4; ++nt) {
      int c = nt * 16 + col;
      *(uint64_t*)(Tsl + c * 512 + ((h0 * 2) ^ ((c & 7) << 4))) = cvt4h(taccS[mt][nt]);
    }
  }
  if (col >= cb && col < cb + NR) {
    int lr = col - cb;
#pragma unroll
    for (int mt = 0; mt < 4; ++mt) {
      int h0 = w * 64 + mt * 16 + khi * 4;
      f32x4 v = taccR[mt] + *(const f32x4*)(b1p + h0);
      *(uint64_t*)(Trl + lr * 512 + h0 * 2) = cvt4h(v);
    }
  }
  __syncthreads();

  // ---- phase 4: edge loop over NR r's ----
  int d0 = w * 32 + col;
  const _Float16* W2p = W2fp + p * 32768;
  f16x8 bv[2][8];
#pragma unroll
  for (int nt = 0; nt < 2; ++nt)
#pragma unroll
    for (int ks = 0; ks < 8; ++ks)
      bv[nt][ks] = *(const f16x8*)(W2p + (d0 + nt * 16) * 256 + ks * 32 + khi * 8);
  const float* b2p = p ? b2_1 : b2_0;
  float b2v[2] = {b2p[d0], b2p[d0 + 16]};

#pragma unroll 1
  for (int r = 0; r < NR; ++r) {
    f32x4 acc[4][2];
#pragma unroll
    for (int mt = 0; mt < 4; ++mt) { acc[mt][0] = z4; acc[mt][1] = z4; }
#pragma unroll
    for (int ks = 0; ks < 8; ++ks) {
      f16x8 trv = *(const f16x8*)(Trl + r * 512 + ks * 64 + khi * 16);
#pragma unroll
      for (int mt = 0; mt < 4; ++mt) {
        int c = mt * 16 + col;
        f16x8 ts = *(const f16x8*)(Tsl + c * 512 +
                                   ((ks * 64 + khi * 16) ^ ((c & 7) << 4)));
        f16x8 zv = {};
        f16x8 a = __builtin_elementwise_max(ts + trv, zv);
        acc[mt][0] = __builtin_amdgcn_mfma_f32_16x16x32_f16(a, bv[0][ks],
                                                            acc[mt][0], 0, 0, 0);
        acc[mt][1] = __builtin_amdgcn_mfma_f32_16x16x32_f16(a, bv[1][ks],
                                                            acc[mt][1], 0, 0, 0);
      }
    }
    int rr = rbase + r;
    const int* arow = arcs + ((size_t)(b * NN + rr)) * NN;
    float s0 = 0.f, s1 = 0.f;
#pragma unroll
    for (int mt = 0; mt < 4; ++mt) {
      const int4 av = *(const int4*)(arow + mt * 16 + khi * 4);
#pragma unroll
      for (int j = 0; j < 4; ++j) {
        int ai = (j == 0) ? av.x : (j == 1) ? av.y : (j == 2) ? av.z : av.w;
        float wgt = p ? (float)ai : 1.0f - (float)ai;
        s0 = fmaf(wgt, fmaxf(acc[mt][0][j] + b2v[0], 0.f), s0);
        s1 = fmaf(wgt, fmaxf(acc[mt][1][j] + b2v[1], 0.f), s1);
      }
    }
    s0 += __shfl_xor(s0, 16); s0 += __shfl_xor(s0, 32);
    s1 += __shfl_xor(s1, 16); s1 += __shfl_xor(s1, 32);
    if (khi == 0) {
      if (NR == 1) {
        float* o = spOut + (size_t)(p * NB + b) * DD;
        o[d0] = s0; o[d0 + 16] = s1;
      } else {
        float* o = spOut + ((size_t)(p * NB + b) * NN + rr) * DD;
        o[d0] = s0; o[d0 + 16] = s1;
      }
    }
  }
}

// out[b][d] = E0[b][0][d] + SpA[0..1] + SpB[0..1] (row 0) + SpC[0..1]
__global__ __launch_bounds__(256) void k_out(const float* __restrict__ E0,
                                             const float* __restrict__ spA,
                                             const float* __restrict__ spB,
                                             const float* __restrict__ spC,
                                             float* __restrict__ out) {
  int i = blockIdx.x * 256 + threadIdx.x;      // 4096
  int b = i >> 7, d = i & 127;
  float acc = E0[(size_t)b * NN * DD + d];
  acc += spA[(size_t)b * NN * DD + d] + spA[(size_t)(NB + b) * NN * DD + d];
  acc += spB[(size_t)b * NN * DD + d] + spB[(size_t)(NB + b) * NN * DD + d];
  acc += spC[(size_t)b * DD + d] + spC[(size_t)(NB + b) * DD + d];
  out[i] = acc;
}

extern "C" void kernel_launch(void* const* d_in, const int* in_sizes, int n_in,
                              void* d_out, int out_size, void* d_ws, size_t ws_size,
                              hipStream_t stream) {
  const int* x       = (const int*)d_in[0];
  const int* arcs    = (const int*)d_in[1];
  const float* table = (const float*)d_in[3];
  const float* W1_0  = (const float*)d_in[4];
  const float* b1_0  = (const float*)d_in[5];
  const float* W2_0  = (const float*)d_in[6];
  const float* b2_0  = (const float*)d_in[7];
  const float* W1_1  = (const float*)d_in[8];
  const float* b1_1  = (const float*)d_in[9];
  const float* W2_1  = (const float*)d_in[10];
  const float* b2_1  = (const float*)d_in[11];
  float* out = (float*)d_out;

  char* ws = (char*)d_ws;
  float* E0        = (float*)ws;                                   // 1 MB
  _Float16* W1fp   = (_Float16*)(ws + (1u << 20));                 // 256 KB
  _Float16* W2fp   = (_Float16*)(ws + (1u << 20) + (256u << 10));  // 128 KB
  float* SpA       = (float*)(ws + (2u << 20));                    // 2 MB
  float* SpB       = (float*)(ws + (4u << 20));                    // 2 MB
  float* SpC       = (float*)(ws + (6u << 20));                    // 32 KB

  k_setup<<<448, 256, 0, stream>>>(x, table, E0, W1_0, W1_1, W2_0, W2_1,
                                   W1fp, W2fp);
  k_fused<0, 4><<<dim3(16, 32, 2), 256, 0, stream>>>(
      E0, E0, E0, SpA, W1fp, W2fp, b1_0, b1_1, b2_0, b2_1, arcs);
  k_fused<1, 4><<<dim3(16, 32, 2), 256, 0, stream>>>(
      E0, SpA, E0, SpB, W1fp, W2fp, b1_0, b1_1, b2_0, b2_1, arcs);
  k_fused<2, 1><<<dim3(1, 32, 2), 256, 0, stream>>>(
      E0, SpA, SpB, SpC, W1fp, W2fp, b1_0, b1_1, b2_0, b2_1, arcs);
  k_out<<<16, 256, 0, stream>>>(E0, SpA, SpB, SpC, out);
}